// Round 1
// baseline (447.594 us; speedup 1.0000x reference)
//
#include <hip/hip_runtime.h>
#include <stdint.h>

#define N_NODES 10000
#define N_EDGES 160000
#define HID 512
#define EDIM 128
#define K1 640
#define BM 64
#define LN_EPS 1e-5f

typedef __attribute__((ext_vector_type(4))) float f32x4;
typedef __attribute__((ext_vector_type(8))) short bf16x8;

__device__ __forceinline__ short f2bf(float f) {
  unsigned u = __float_as_uint(f);
  u += 0x7fff + ((u >> 16) & 1);
  return (short)(u >> 16);
}
__device__ __forceinline__ float gelu_f(float x) {
  return 0.5f * x * (1.0f + erff(x * 0.70710678118654752440f));
}

#define GLDS(g, l) __builtin_amdgcn_global_load_lds( \
    (const __attribute__((address_space(1))) void*)(g), \
    (__attribute__((address_space(3))) void*)(l), 16, 0, 0)

// ---------------------------------------------------------------------------
// Edge kernel: h = gelu([ns[src] | ee] @ w1 + b1); atomicAdd into hsum[tgt]
// ---------------------------------------------------------------------------
__global__ __launch_bounds__(512, 4) void edge_mlp_kernel(
    const float* __restrict__ node_state, const float* __restrict__ edge_emb,
    const int* __restrict__ srcs, const int* __restrict__ tgts,
    const short* __restrict__ w1T,  // [512 n][640 k] bf16
    const float* __restrict__ b1,
    float* __restrict__ hsum)
{
  __shared__ short As[2][BM * 32];     // 64 rows x 32 k, XOR-permuted 16B units
  __shared__ short Bs[2][HID * 32];    // 512 n x 32 k, XOR-permuted 16B units
  __shared__ int src_l[BM], tgt_l[BM];

  const int tid = threadIdx.x;
  const int lane = tid & 63;
  const int wv = tid >> 6;
  const int r16 = lane & 15, q4 = lane >> 4;
  const int e0 = blockIdx.x * BM;

  if (tid < BM) { src_l[tid] = srcs[e0 + tid]; tgt_l[tid] = tgts[e0 + tid]; }

  float b1v[4];
#pragma unroll
  for (int ni = 0; ni < 4; ++ni) b1v[ni] = b1[wv * 64 + ni * 16 + r16];

  __syncthreads();

  const int arow = tid >> 2, auk = tid & 3;
  f32x4 a0, a1;

  auto loadA = [&](int k0) {
    if (tid < 256) {
      int k = k0 + auk * 8;
      const float* p = (k < HID)
          ? node_state + (size_t)src_l[arow] * HID + k
          : edge_emb + (size_t)(e0 + arow) * EDIM + (k - HID);
      a0 = *(const f32x4*)p; a1 = *(const f32x4*)(p + 4);
    }
  };
  auto writeA = [&](int buf) {
    if (tid < 256) {
      bf16x8 v;
      v[0] = f2bf(a0[0]); v[1] = f2bf(a0[1]); v[2] = f2bf(a0[2]); v[3] = f2bf(a0[3]);
      v[4] = f2bf(a1[0]); v[5] = f2bf(a1[1]); v[6] = f2bf(a1[2]); v[7] = f2bf(a1[3]);
      int pos = arow * 4 + ((auk + (arow >> 1)) & 3);
      *(bf16x8*)(&As[buf][pos * 8]) = v;
    }
  };
  auto stageB = [&](const short* wT, int kstride, int k0, int buf) {
#pragma unroll
    for (int i = 0; i < 4; ++i) {
      int q = i * 512 + tid;                  // LDS 16B-unit position
      int n = q >> 2;
      int uk = ((q & 3) - (n >> 1)) & 3;      // inverse of read-side XOR
      const short* g = wT + (size_t)n * kstride + k0 + uk * 8;
      short* l = &Bs[buf][(i * 512 + wv * 64) * 8];  // wave-uniform base
      GLDS(g, l);
    }
  };

  f32x4 acc[4][4] = {};

  auto mma = [&](int buf) {
    bf16x8 af[4];
#pragma unroll
    for (int mi = 0; mi < 4; ++mi) {
      int row = mi * 16 + r16;
      int pos = row * 4 + ((q4 + (row >> 1)) & 3);
      af[mi] = *(const bf16x8*)(&As[buf][pos * 8]);
    }
#pragma unroll
    for (int ni = 0; ni < 4; ++ni) {
      int n = wv * 64 + ni * 16 + r16;
      int pos = n * 4 + ((q4 + (n >> 1)) & 3);
      bf16x8 bfr = *(const bf16x8*)(&Bs[buf][pos * 8]);
#pragma unroll
      for (int mi = 0; mi < 4; ++mi)
        acc[mi][ni] = __builtin_amdgcn_mfma_f32_16x16x32_bf16(af[mi], bfr, acc[mi][ni], 0, 0, 0);
    }
  };

  stageB(w1T, K1, 0, 0);
  loadA(0); writeA(0);
  __syncthreads();
#pragma unroll 1
  for (int s = 0; s < 20; ++s) {
    int cur = s & 1, nxt = cur ^ 1;
    if (s < 19) { stageB(w1T, K1, (s + 1) * 32, nxt); loadA((s + 1) * 32); }
    mma(cur);
    if (s < 19) writeA(nxt);
    __syncthreads();
  }

  // epilogue: bias + gelu + atomic scatter of h into hsum[tgt]
#pragma unroll
  for (int mi = 0; mi < 4; ++mi) {
#pragma unroll
    for (int j = 0; j < 4; ++j) {
      int row = mi * 16 + q4 * 4 + j;
      int t = tgt_l[row];
      float* dst = hsum + (size_t)t * HID + wv * 64 + r16;
#pragma unroll
      for (int ni = 0; ni < 4; ++ni) {
        float v = gelu_f(acc[mi][ni][j] + b1v[ni]);
        atomicAdd(dst + ni * 16, v);
      }
    }
  }
}

// ---------------------------------------------------------------------------
// Node kernel: updated = [ns | hsum/cnt] @ [[self_w],[W]] + biases;
// out = LN(ns + gelu(updated)) * gamma + beta
// ---------------------------------------------------------------------------
__global__ __launch_bounds__(512, 2) void node_update_kernel(
    const float* __restrict__ node_state, const float* __restrict__ hsum,
    const float* __restrict__ cnt,
    const short* __restrict__ swT, const short* __restrict__ WT,  // [512 n][512 k]
    const float* __restrict__ self_b, const float* __restrict__ agg_b,
    const float* __restrict__ bvec,
    const float* __restrict__ gamma, const float* __restrict__ beta,
    float* __restrict__ out)
{
  __shared__ short As[2][BM * 32];
  __shared__ short Bs[2][HID * 32];
  __shared__ float invc_l[BM], cfl[BM];
  __shared__ float wsum[8][BM], wsq[8][BM];
  __shared__ float stats[BM][2];

  const int tid = threadIdx.x, lane = tid & 63, wv = tid >> 6;
  const int r16 = lane & 15, q4 = lane >> 4;
  const int n0 = blockIdx.x * BM;

  if (tid < BM) {
    int g = n0 + tid;
    float c = (g < N_NODES) ? cnt[g] : 0.0f;
    invc_l[tid] = 1.0f / fmaxf(c, 1.0f);
    cfl[tid] = (c > 0.5f) ? 1.0f : 0.0f;
  }

  float bb[4], bv[4], gam[4], bet[4];
#pragma unroll
  for (int ni = 0; ni < 4; ++ni) {
    int c = wv * 64 + ni * 16 + r16;
    bb[ni] = self_b[c] + agg_b[c];
    bv[ni] = bvec[c];
    gam[ni] = gamma[c]; bet[ni] = beta[c];
  }
  __syncthreads();

  const int arow = tid >> 2, auk = tid & 3;
  const int ga = min(n0 + arow, N_NODES - 1);
  f32x4 a0, a1;

  auto loadA = [&](int k0) {
    if (tid < 256) {
      int k = k0 + auk * 8;
      const float* p = (k < HID) ? node_state + (size_t)ga * HID + k
                                 : hsum + (size_t)ga * HID + (k - HID);
      a0 = *(const f32x4*)p; a1 = *(const f32x4*)(p + 4);
      if (k >= HID) { float s = invc_l[arow]; a0 *= s; a1 *= s; }
    }
  };
  auto writeA = [&](int buf) {
    if (tid < 256) {
      bf16x8 v;
      v[0] = f2bf(a0[0]); v[1] = f2bf(a0[1]); v[2] = f2bf(a0[2]); v[3] = f2bf(a0[3]);
      v[4] = f2bf(a1[0]); v[5] = f2bf(a1[1]); v[6] = f2bf(a1[2]); v[7] = f2bf(a1[3]);
      int pos = arow * 4 + ((auk + (arow >> 1)) & 3);
      *(bf16x8*)(&As[buf][pos * 8]) = v;
    }
  };
  auto stageB = [&](const short* wT, int k0, int buf) {
#pragma unroll
    for (int i = 0; i < 4; ++i) {
      int q = i * 512 + tid;
      int n = q >> 2;
      int uk = ((q & 3) - (n >> 1)) & 3;
      const short* g = wT + (size_t)n * HID + k0 + uk * 8;
      short* l = &Bs[buf][(i * 512 + wv * 64) * 8];
      GLDS(g, l);
    }
  };

  f32x4 acc[4][4] = {};

  auto mma = [&](int buf) {
    bf16x8 af[4];
#pragma unroll
    for (int mi = 0; mi < 4; ++mi) {
      int row = mi * 16 + r16;
      int pos = row * 4 + ((q4 + (row >> 1)) & 3);
      af[mi] = *(const bf16x8*)(&As[buf][pos * 8]);
    }
#pragma unroll
    for (int ni = 0; ni < 4; ++ni) {
      int n = wv * 64 + ni * 16 + r16;
      int pos = n * 4 + ((q4 + (n >> 1)) & 3);
      bf16x8 bfr = *(const bf16x8*)(&Bs[buf][pos * 8]);
#pragma unroll
      for (int mi = 0; mi < 4; ++mi)
        acc[mi][ni] = __builtin_amdgcn_mfma_f32_16x16x32_bf16(af[mi], bfr, acc[mi][ni], 0, 0, 0);
    }
  };

  stageB(swT, 0, 0);
  loadA(0); writeA(0);
  __syncthreads();
#pragma unroll 1
  for (int s = 0; s < 32; ++s) {
    int cur = s & 1, nxt = cur ^ 1;
    if (s < 31) {
      int k0 = (s + 1) * 32;
      if (k0 < HID) stageB(swT, k0, nxt); else stageB(WT, k0 - HID, nxt);
      loadA(k0);
    }
    mma(cur);
    if (s < 31) writeA(nxt);
    __syncthreads();
  }

  // epilogue: bias + flag*bvec, gelu, residual; row LN via shfl + LDS
  float ps[4][4], ps2[4][4];
#pragma unroll
  for (int mi = 0; mi < 4; ++mi)
#pragma unroll
    for (int j = 0; j < 4; ++j) {
      int row = mi * 16 + q4 * 4 + j;
      int g = min(n0 + row, N_NODES - 1);
      float fl = cfl[row];
      float s1 = 0.f, s2 = 0.f;
#pragma unroll
      for (int ni = 0; ni < 4; ++ni) {
        float u = acc[mi][ni][j] + bb[ni] + fl * bv[ni];
        float ns = node_state[(size_t)g * HID + wv * 64 + ni * 16 + r16];
        float x = ns + gelu_f(u);
        acc[mi][ni][j] = x;
        s1 += x; s2 += x * x;
      }
      ps[mi][j] = s1; ps2[mi][j] = s2;
    }
#pragma unroll
  for (int mi = 0; mi < 4; ++mi)
#pragma unroll
    for (int j = 0; j < 4; ++j) {
#pragma unroll
      for (int m = 1; m < 16; m <<= 1) {
        ps[mi][j] += __shfl_xor(ps[mi][j], m, 64);
        ps2[mi][j] += __shfl_xor(ps2[mi][j], m, 64);
      }
    }
  if (r16 == 0) {
#pragma unroll
    for (int mi = 0; mi < 4; ++mi)
#pragma unroll
      for (int j = 0; j < 4; ++j) {
        int row = mi * 16 + q4 * 4 + j;
        wsum[wv][row] = ps[mi][j]; wsq[wv][row] = ps2[mi][j];
      }
  }
  __syncthreads();
  if (tid < BM) {
    float s1 = 0.f, s2 = 0.f;
#pragma unroll
    for (int k = 0; k < 8; ++k) { s1 += wsum[k][tid]; s2 += wsq[k][tid]; }
    float mu = s1 * (1.0f / HID);
    float var = s2 * (1.0f / HID) - mu * mu;
    stats[tid][0] = mu; stats[tid][1] = rsqrtf(var + LN_EPS);
  }
  __syncthreads();
#pragma unroll
  for (int mi = 0; mi < 4; ++mi)
#pragma unroll
    for (int j = 0; j < 4; ++j) {
      int row = mi * 16 + q4 * 4 + j;
      int g = n0 + row;
      if (g < N_NODES) {
        float mu = stats[row][0], rs = stats[row][1];
#pragma unroll
        for (int ni = 0; ni < 4; ++ni)
          out[(size_t)g * HID + wv * 64 + ni * 16 + r16] =
              (acc[mi][ni][j] - mu) * rs * gam[ni] + bet[ni];
      }
    }
}

// ---------------------------------------------------------------------------
// Helpers: W = w2 @ agg_w (f32), bvec = b2 @ agg_w; transposed bf16 weights;
// in-degree counts
// ---------------------------------------------------------------------------
__global__ void wcombine_kernel(const float* __restrict__ w2,
                                const float* __restrict__ aggw,
                                const float* __restrict__ b2,
                                float* __restrict__ Wf, float* __restrict__ bvec)
{
  __shared__ float rowbuf[HID];
  int k = blockIdx.x;  // 0..511 rows of w2; 512 => b2
  const float* row = (k == HID) ? b2 : (w2 + (size_t)k * HID);
  int n = threadIdx.x;
  rowbuf[n] = row[n];
  __syncthreads();
  float s = 0.f;
  for (int j = 0; j < HID; ++j) s = fmaf(rowbuf[j], aggw[(size_t)j * HID + n], s);
  if (k == HID) bvec[n] = s; else Wf[(size_t)k * HID + n] = s;
}

__global__ void cvt_transpose_kernel(const float* __restrict__ src,
                                     short* __restrict__ dst, int K, int Nn)
{
  int id = blockIdx.x * 256 + threadIdx.x;   // over n*K + k
  if (id < K * Nn) {
    int n = id / K, k = id - n * K;
    dst[id] = f2bf(src[(size_t)k * Nn + n]);
  }
}

__global__ void count_kernel(const int* __restrict__ tgt, float* __restrict__ cnt)
{
  int i = blockIdx.x * 256 + threadIdx.x;
  if (i < N_EDGES) atomicAdd(&cnt[tgt[i]], 1.0f);
}

// ---------------------------------------------------------------------------
extern "C" void kernel_launch(void* const* d_in, const int* in_sizes, int n_in,
                              void* d_out, int out_size, void* d_ws, size_t ws_size,
                              hipStream_t stream)
{
  const float* node_state = (const float*)d_in[0];
  const int*   eidx       = (const int*)d_in[1];
  const float* edge_emb   = (const float*)d_in[2];
  const float* msg_w1     = (const float*)d_in[3];
  const float* msg_b1     = (const float*)d_in[4];
  const float* msg_w2     = (const float*)d_in[5];
  // msg_b2 = d_in[6]
  const float* self_w     = (const float*)d_in[7];
  const float* self_b     = (const float*)d_in[8];
  const float* agg_w      = (const float*)d_in[9];
  const float* agg_b      = (const float*)d_in[10];
  const float* ln_gamma   = (const float*)d_in[11];
  const float* ln_beta    = (const float*)d_in[12];
  const float* msg_b2     = (const float*)d_in[6];

  const int* srcs = eidx;
  const int* tgts = eidx + N_EDGES;
  float* out = (float*)d_out;

  char* ws = (char*)d_ws;
  float* hsum = (float*)ws;                         // 20,480,000 B
  float* cnt  = (float*)(ws + 20480000);            //     40,000 B
  short* w1T  = (short*)(ws + 20520192);            //    655,360 B
  short* swT  = (short*)(ws + 21175552);            //    524,288 B
  short* WT   = (short*)(ws + 21699840);            //    524,288 B
  float* Wf   = (float*)(ws + 22224128);            //  1,048,576 B
  float* bvec = (float*)(ws + 23272704);            //      2,048 B

  hipMemsetAsync(d_ws, 0, 20520000, stream);  // zero hsum + cnt

  cvt_transpose_kernel<<<(HID * K1 + 255) / 256, 256, 0, stream>>>(msg_w1, w1T, K1, HID);
  cvt_transpose_kernel<<<(HID * HID + 255) / 256, 256, 0, stream>>>(self_w, swT, HID, HID);
  wcombine_kernel<<<HID + 1, HID, 0, stream>>>(msg_w2, agg_w, msg_b2, Wf, bvec);
  cvt_transpose_kernel<<<(HID * HID + 255) / 256, 256, 0, stream>>>(Wf, WT, HID, HID);
  count_kernel<<<(N_EDGES + 255) / 256, 256, 0, stream>>>(tgts, cnt);

  edge_mlp_kernel<<<N_EDGES / BM, 512, 0, stream>>>(
      node_state, edge_emb, srcs, tgts, w1T, msg_b1, hsum);

  node_update_kernel<<<(N_NODES + BM - 1) / BM, 512, 0, stream>>>(
      node_state, hsum, cnt, swT, WT, self_b, agg_b, bvec, ln_gamma, ln_beta, out);
}

// Round 2
// 374.810 us; speedup vs baseline: 1.1942x; 1.1942x over previous
//
#include <hip/hip_runtime.h>
#include <stdint.h>

#define N_NODES 10000
#define N_EDGES 160000
#define HID 512
#define EDIM 128
#define K1 640
#define BM 64
#define LN_EPS 1e-5f

typedef __attribute__((ext_vector_type(4))) float f32x4;
typedef __attribute__((ext_vector_type(8))) short bf16x8;

__device__ __forceinline__ short f2bf(float f) {
  unsigned u = __float_as_uint(f);
  u += 0x7fff + ((u >> 16) & 1);
  return (short)(u >> 16);
}
__device__ __forceinline__ float bf2f(short s) {
  return __uint_as_float(((unsigned)(unsigned short)s) << 16);
}
__device__ __forceinline__ float gelu_f(float x) {
  return 0.5f * x * (1.0f + erff(x * 0.70710678118654752440f));
}

#define GLDS(g, l) __builtin_amdgcn_global_load_lds( \
    (const __attribute__((address_space(1))) void*)(g), \
    (__attribute__((address_space(3))) void*)(l), 16, 0, 0)

// ---------------------------------------------------------------------------
// Edge kernel: h = gelu([ns[src] | ee] @ w1 + b1)
// MODE 0: atomicAdd rows into hsum[tgt] (fallback, small workspace)
// MODE 1: store h (bf16) to hs[edge] for CSR gather
// ---------------------------------------------------------------------------
template <int MODE>
__global__ __launch_bounds__(512, 4) void edge_mlp_kernel(
    const float* __restrict__ node_state, const float* __restrict__ edge_emb,
    const int* __restrict__ srcs, const int* __restrict__ tgts,
    const short* __restrict__ w1T,  // [512 n][640 k] bf16
    const float* __restrict__ b1,
    float* __restrict__ hsum, short* __restrict__ hs)
{
  __shared__ short As[2][BM * 32];     // 64 rows x 32 k, XOR-permuted 16B units
  __shared__ short Bs[2][HID * 32];    // 512 n x 32 k, XOR-permuted 16B units
  __shared__ int src_l[BM], tgt_l[BM];

  const int tid = threadIdx.x;
  const int lane = tid & 63;
  const int wv = tid >> 6;
  const int r16 = lane & 15, q4 = lane >> 4;
  const int e0 = blockIdx.x * BM;

  if (tid < BM) {
    src_l[tid] = srcs[e0 + tid];
    if (MODE == 0) tgt_l[tid] = tgts[e0 + tid];
  }

  float b1v[4];
#pragma unroll
  for (int ni = 0; ni < 4; ++ni) b1v[ni] = b1[wv * 64 + ni * 16 + r16];

  __syncthreads();

  const int arow = tid >> 2, auk = tid & 3;
  f32x4 a0, a1;

  auto loadA = [&](int k0) {
    if (tid < 256) {
      int k = k0 + auk * 8;
      const float* p = (k < HID)
          ? node_state + (size_t)src_l[arow] * HID + k
          : edge_emb + (size_t)(e0 + arow) * EDIM + (k - HID);
      a0 = *(const f32x4*)p; a1 = *(const f32x4*)(p + 4);
    }
  };
  auto writeA = [&](int buf) {
    if (tid < 256) {
      bf16x8 v;
      v[0] = f2bf(a0[0]); v[1] = f2bf(a0[1]); v[2] = f2bf(a0[2]); v[3] = f2bf(a0[3]);
      v[4] = f2bf(a1[0]); v[5] = f2bf(a1[1]); v[6] = f2bf(a1[2]); v[7] = f2bf(a1[3]);
      int pos = arow * 4 + ((auk + (arow >> 1)) & 3);
      *(bf16x8*)(&As[buf][pos * 8]) = v;
    }
  };
  auto stageB = [&](int k0, int buf) {
#pragma unroll
    for (int i = 0; i < 4; ++i) {
      int q = i * 512 + tid;                  // LDS 16B-unit position
      int n = q >> 2;
      int uk = ((q & 3) - (n >> 1)) & 3;      // inverse of read-side XOR
      const short* g = w1T + (size_t)n * K1 + k0 + uk * 8;
      short* l = &Bs[buf][(i * 512 + wv * 64) * 8];  // wave-uniform base
      GLDS(g, l);
    }
  };

  f32x4 acc[4][4] = {};

  auto mma = [&](int buf) {
    bf16x8 af[4];
#pragma unroll
    for (int mi = 0; mi < 4; ++mi) {
      int row = mi * 16 + r16;
      int pos = row * 4 + ((q4 + (row >> 1)) & 3);
      af[mi] = *(const bf16x8*)(&As[buf][pos * 8]);
    }
#pragma unroll
    for (int ni = 0; ni < 4; ++ni) {
      int n = wv * 64 + ni * 16 + r16;
      int pos = n * 4 + ((q4 + (n >> 1)) & 3);
      bf16x8 bfr = *(const bf16x8*)(&Bs[buf][pos * 8]);
#pragma unroll
      for (int mi = 0; mi < 4; ++mi)
        acc[mi][ni] = __builtin_amdgcn_mfma_f32_16x16x32_bf16(af[mi], bfr, acc[mi][ni], 0, 0, 0);
    }
  };

  stageB(0, 0);
  loadA(0); writeA(0);
  __syncthreads();
#pragma unroll 1
  for (int s = 0; s < 20; ++s) {
    int cur = s & 1, nxt = cur ^ 1;
    if (s < 19) { stageB((s + 1) * 32, nxt); loadA((s + 1) * 32); }
    mma(cur);
    if (s < 19) writeA(nxt);
    __syncthreads();
  }

  if (MODE == 0) {
    // epilogue: bias + gelu + atomic scatter of h into hsum[tgt]
#pragma unroll
    for (int mi = 0; mi < 4; ++mi) {
#pragma unroll
      for (int j = 0; j < 4; ++j) {
        int row = mi * 16 + q4 * 4 + j;
        int t = tgt_l[row];
        float* dst = hsum + (size_t)t * HID + wv * 64 + r16;
#pragma unroll
        for (int ni = 0; ni < 4; ++ni) {
          float v = gelu_f(acc[mi][ni][j] + b1v[ni]);
          atomicAdd(dst + ni * 16, v);
        }
      }
    }
  } else {
    // epilogue: bias + gelu -> LDS repack (per-wave 64x64 tile) -> bf16 stores
    short* tile = &Bs[0][0] + wv * 4096;  // 64 rows x 64 cols bf16, 8 KB/wave
#pragma unroll
    for (int mi = 0; mi < 4; ++mi)
#pragma unroll
      for (int j = 0; j < 4; ++j) {
        int row = mi * 16 + q4 * 4 + j;
#pragma unroll
        for (int ni = 0; ni < 4; ++ni)
          tile[row * 64 + ni * 16 + r16] = f2bf(gelu_f(acc[mi][ni][j] + b1v[ni]));
      }
#pragma unroll
    for (int it = 0; it < 8; ++it) {
      int row = it * 8 + (lane >> 3);
      int c8 = ((lane & 7) + row) & 7;  // rotate within 128B row segment
      bf16x8 v = *(const bf16x8*)&tile[row * 64 + c8 * 8];
      *(bf16x8*)&hs[(size_t)(e0 + row) * HID + wv * 64 + c8 * 8] = v;
    }
  }
}

// ---------------------------------------------------------------------------
// Node kernel: updated = [ns | hmean] @ [[self_w],[W]] + biases;
// out = LN(ns + gelu(updated)) * gamma + beta
// ---------------------------------------------------------------------------
__global__ __launch_bounds__(512, 2) void node_update_kernel(
    const float* __restrict__ node_state, const float* __restrict__ hmean,
    const int* __restrict__ icnt,
    const short* __restrict__ swT, const short* __restrict__ WT,  // [512 n][512 k]
    const float* __restrict__ self_b, const float* __restrict__ agg_b,
    const float* __restrict__ bvec,
    const float* __restrict__ gamma, const float* __restrict__ beta,
    float* __restrict__ out)
{
  __shared__ short As[2][BM * 32];
  __shared__ short Bs[2][HID * 32];
  __shared__ float cfl[BM];
  __shared__ float wsum[8][BM], wsq[8][BM];
  __shared__ float stats[BM][2];

  const int tid = threadIdx.x, lane = tid & 63, wv = tid >> 6;
  const int r16 = lane & 15, q4 = lane >> 4;
  const int n0 = blockIdx.x * BM;

  if (tid < BM) {
    int g = n0 + tid;
    cfl[tid] = (g < N_NODES && icnt[g] > 0) ? 1.0f : 0.0f;
  }

  float bb[4], bv[4], gam[4], bet[4];
#pragma unroll
  for (int ni = 0; ni < 4; ++ni) {
    int c = wv * 64 + ni * 16 + r16;
    bb[ni] = self_b[c] + agg_b[c];
    bv[ni] = bvec[c];
    gam[ni] = gamma[c]; bet[ni] = beta[c];
  }
  __syncthreads();

  const int arow = tid >> 2, auk = tid & 3;
  const int ga = min(n0 + arow, N_NODES - 1);
  f32x4 a0, a1;

  auto loadA = [&](int k0) {
    if (tid < 256) {
      int k = k0 + auk * 8;
      const float* p = (k < HID) ? node_state + (size_t)ga * HID + k
                                 : hmean + (size_t)ga * HID + (k - HID);
      a0 = *(const f32x4*)p; a1 = *(const f32x4*)(p + 4);
    }
  };
  auto writeA = [&](int buf) {
    if (tid < 256) {
      bf16x8 v;
      v[0] = f2bf(a0[0]); v[1] = f2bf(a0[1]); v[2] = f2bf(a0[2]); v[3] = f2bf(a0[3]);
      v[4] = f2bf(a1[0]); v[5] = f2bf(a1[1]); v[6] = f2bf(a1[2]); v[7] = f2bf(a1[3]);
      int pos = arow * 4 + ((auk + (arow >> 1)) & 3);
      *(bf16x8*)(&As[buf][pos * 8]) = v;
    }
  };
  auto stageB = [&](const short* wT, int k0, int buf) {
#pragma unroll
    for (int i = 0; i < 4; ++i) {
      int q = i * 512 + tid;
      int n = q >> 2;
      int uk = ((q & 3) - (n >> 1)) & 3;
      const short* g = wT + (size_t)n * HID + k0 + uk * 8;
      short* l = &Bs[buf][(i * 512 + wv * 64) * 8];
      GLDS(g, l);
    }
  };

  f32x4 acc[4][4] = {};

  auto mma = [&](int buf) {
    bf16x8 af[4];
#pragma unroll
    for (int mi = 0; mi < 4; ++mi) {
      int row = mi * 16 + r16;
      int pos = row * 4 + ((q4 + (row >> 1)) & 3);
      af[mi] = *(const bf16x8*)(&As[buf][pos * 8]);
    }
#pragma unroll
    for (int ni = 0; ni < 4; ++ni) {
      int n = wv * 64 + ni * 16 + r16;
      int pos = n * 4 + ((q4 + (n >> 1)) & 3);
      bf16x8 bfr = *(const bf16x8*)(&Bs[buf][pos * 8]);
#pragma unroll
      for (int mi = 0; mi < 4; ++mi)
        acc[mi][ni] = __builtin_amdgcn_mfma_f32_16x16x32_bf16(af[mi], bfr, acc[mi][ni], 0, 0, 0);
    }
  };

  stageB(swT, 0, 0);
  loadA(0); writeA(0);
  __syncthreads();
#pragma unroll 1
  for (int s = 0; s < 32; ++s) {
    int cur = s & 1, nxt = cur ^ 1;
    if (s < 31) {
      int k0 = (s + 1) * 32;
      if (k0 < HID) stageB(swT, k0, nxt); else stageB(WT, k0 - HID, nxt);
      loadA(k0);
    }
    mma(cur);
    if (s < 31) writeA(nxt);
    __syncthreads();
  }

  // epilogue: bias + flag*bvec, gelu, residual; row LN via shfl + LDS
  float ps[4][4], ps2[4][4];
#pragma unroll
  for (int mi = 0; mi < 4; ++mi)
#pragma unroll
    for (int j = 0; j < 4; ++j) {
      int row = mi * 16 + q4 * 4 + j;
      int g = min(n0 + row, N_NODES - 1);
      float fl = cfl[row];
      float s1 = 0.f, s2 = 0.f;
#pragma unroll
      for (int ni = 0; ni < 4; ++ni) {
        float u = acc[mi][ni][j] + bb[ni] + fl * bv[ni];
        float ns = node_state[(size_t)g * HID + wv * 64 + ni * 16 + r16];
        float x = ns + gelu_f(u);
        acc[mi][ni][j] = x;
        s1 += x; s2 += x * x;
      }
      ps[mi][j] = s1; ps2[mi][j] = s2;
    }
#pragma unroll
  for (int mi = 0; mi < 4; ++mi)
#pragma unroll
    for (int j = 0; j < 4; ++j) {
#pragma unroll
      for (int m = 1; m < 16; m <<= 1) {
        ps[mi][j] += __shfl_xor(ps[mi][j], m, 64);
        ps2[mi][j] += __shfl_xor(ps2[mi][j], m, 64);
      }
    }
  if (r16 == 0) {
#pragma unroll
    for (int mi = 0; mi < 4; ++mi)
#pragma unroll
      for (int j = 0; j < 4; ++j) {
        int row = mi * 16 + q4 * 4 + j;
        wsum[wv][row] = ps[mi][j]; wsq[wv][row] = ps2[mi][j];
      }
  }
  __syncthreads();
  if (tid < BM) {
    float s1 = 0.f, s2 = 0.f;
#pragma unroll
    for (int k = 0; k < 8; ++k) { s1 += wsum[k][tid]; s2 += wsq[k][tid]; }
    float mu = s1 * (1.0f / HID);
    float var = s2 * (1.0f / HID) - mu * mu;
    stats[tid][0] = mu; stats[tid][1] = rsqrtf(var + LN_EPS);
  }
  __syncthreads();
#pragma unroll
  for (int mi = 0; mi < 4; ++mi)
#pragma unroll
    for (int j = 0; j < 4; ++j) {
      int row = mi * 16 + q4 * 4 + j;
      int g = n0 + row;
      if (g < N_NODES) {
        float mu = stats[row][0], rs = stats[row][1];
#pragma unroll
        for (int ni = 0; ni < 4; ++ni)
          out[(size_t)g * HID + wv * 64 + ni * 16 + r16] =
              (acc[mi][ni][j] - mu) * rs * gam[ni] + bet[ni];
      }
    }
}

// ---------------------------------------------------------------------------
// CSR build + gather-mean
// ---------------------------------------------------------------------------
__global__ void count_int_kernel(const int* __restrict__ tgt, int* __restrict__ icnt)
{
  int i = blockIdx.x * 256 + threadIdx.x;
  if (i < N_EDGES) atomicAdd(&icnt[tgt[i]], 1);
}

__global__ __launch_bounds__(256) void scan_kernel(const int* __restrict__ icnt,
                                                   int* __restrict__ off,
                                                   int* __restrict__ cursor)
{
  __shared__ int sums[256];
  const int t = threadIdx.x;
  const int CH = 40;  // 256*40 = 10240 >= N_NODES
  int loc[CH];
  int s = 0;
#pragma unroll
  for (int i = 0; i < CH; ++i) {
    int idx = t * CH + i;
    int v = (idx < N_NODES) ? icnt[idx] : 0;
    loc[i] = s; s += v;
  }
  sums[t] = s;
  __syncthreads();
  for (int d = 1; d < 256; d <<= 1) {
    int v = (t >= d) ? sums[t - d] : 0;
    __syncthreads();
    sums[t] += v;
    __syncthreads();
  }
  int base = (t == 0) ? 0 : sums[t - 1];
#pragma unroll
  for (int i = 0; i < CH; ++i) {
    int idx = t * CH + i;
    if (idx < N_NODES) { off[idx] = base + loc[i]; cursor[idx] = base + loc[i]; }
  }
  if (t == 255) off[N_NODES] = sums[255];
}

__global__ void fill_kernel(const int* __restrict__ tgt, int* __restrict__ cursor,
                            int* __restrict__ sorted)
{
  int i = blockIdx.x * 256 + threadIdx.x;
  if (i < N_EDGES) {
    int tg = tgt[i];
    int p = atomicAdd(&cursor[tg], 1);
    sorted[p] = i;
  }
}

__global__ __launch_bounds__(256) void gather_mean_kernel(
    const short* __restrict__ hs, const int* __restrict__ off,
    const int* __restrict__ sorted, float* __restrict__ hmean)
{
  int node = blockIdx.x * 4 + (threadIdx.x >> 6);
  int lane = threadIdx.x & 63;
  if (node >= N_NODES) return;
  int b = off[node], e = off[node + 1];
  float acc[8] = {0.f, 0.f, 0.f, 0.f, 0.f, 0.f, 0.f, 0.f};
  int i = b;
  for (; i + 1 < e; i += 2) {
    int e0 = sorted[i], e1 = sorted[i + 1];
    bf16x8 v0 = *(const bf16x8*)&hs[(size_t)e0 * HID + lane * 8];
    bf16x8 v1 = *(const bf16x8*)&hs[(size_t)e1 * HID + lane * 8];
#pragma unroll
    for (int j = 0; j < 8; ++j) acc[j] += bf2f(v0[j]) + bf2f(v1[j]);
  }
  if (i < e) {
    int e0 = sorted[i];
    bf16x8 v0 = *(const bf16x8*)&hs[(size_t)e0 * HID + lane * 8];
#pragma unroll
    for (int j = 0; j < 8; ++j) acc[j] += bf2f(v0[j]);
  }
  float inv = 1.0f / (float)max(e - b, 1);
  f32x4 o0, o1;
#pragma unroll
  for (int j = 0; j < 4; ++j) { o0[j] = acc[j] * inv; o1[j] = acc[4 + j] * inv; }
  float* dst = hmean + (size_t)node * HID + lane * 8;
  *(f32x4*)dst = o0;
  *(f32x4*)(dst + 4) = o1;
}

__global__ void mean_div_kernel(float* __restrict__ hsum, const int* __restrict__ icnt)
{
  int id = blockIdx.x * 256 + threadIdx.x;
  if (id < N_NODES * HID) {
    int n = id >> 9;
    hsum[id] *= 1.0f / (float)max(icnt[n], 1);
  }
}

// ---------------------------------------------------------------------------
// Weight prep: W = w2 @ agg_w (f32), bvec = b2 @ agg_w; bf16 transposes
// ---------------------------------------------------------------------------
__global__ void wcombine_kernel(const float* __restrict__ w2,
                                const float* __restrict__ aggw,
                                const float* __restrict__ b2,
                                float* __restrict__ Wf, float* __restrict__ bvec)
{
  __shared__ float rowbuf[HID];
  int k = blockIdx.x;  // 0..511 rows of w2; 512 => b2
  const float* row = (k == HID) ? b2 : (w2 + (size_t)k * HID);
  int n = threadIdx.x;
  rowbuf[n] = row[n];
  __syncthreads();
  float s = 0.f;
  for (int j = 0; j < HID; ++j) s = fmaf(rowbuf[j], aggw[(size_t)j * HID + n], s);
  if (k == HID) bvec[n] = s; else Wf[(size_t)k * HID + n] = s;
}

__global__ void cvt_transpose_kernel(const float* __restrict__ src,
                                     short* __restrict__ dst, int K, int Nn)
{
  int id = blockIdx.x * 256 + threadIdx.x;   // over n*K + k
  if (id < K * Nn) {
    int n = id / K, k = id - n * K;
    dst[id] = f2bf(src[(size_t)k * Nn + n]);
  }
}

// ---------------------------------------------------------------------------
extern "C" void kernel_launch(void* const* d_in, const int* in_sizes, int n_in,
                              void* d_out, int out_size, void* d_ws, size_t ws_size,
                              hipStream_t stream)
{
  const float* node_state = (const float*)d_in[0];
  const int*   eidx       = (const int*)d_in[1];
  const float* edge_emb   = (const float*)d_in[2];
  const float* msg_w1     = (const float*)d_in[3];
  const float* msg_b1     = (const float*)d_in[4];
  const float* msg_w2     = (const float*)d_in[5];
  const float* msg_b2     = (const float*)d_in[6];
  const float* self_w     = (const float*)d_in[7];
  const float* self_b     = (const float*)d_in[8];
  const float* agg_w      = (const float*)d_in[9];
  const float* agg_b      = (const float*)d_in[10];
  const float* ln_gamma   = (const float*)d_in[11];
  const float* ln_beta    = (const float*)d_in[12];

  const int* srcs = eidx;
  const int* tgts = eidx + N_EDGES;
  float* out = (float*)d_out;
  char* ws = (char*)d_ws;

  if (ws_size >= (size_t)187900000) {
    // ---- CSR gather path ----
    short* hs    = (short*)ws;                        // 163,840,000
    float* hmean = (float*)(ws + 163840000);          //  20,480,000
    int* icnt    = (int*)(ws + 184320000);            //      40,000
    int* off     = (int*)(ws + 184360192);            //      40,004
    int* cursor  = (int*)(ws + 184400384);            //      40,004
    int* sorted  = (int*)(ws + 184440576);            //     640,000
    short* w1T   = (short*)(ws + 185080576);          //     655,360
    short* swT   = (short*)(ws + 185735936);          //     524,288
    short* WT    = (short*)(ws + 186260224);          //     524,288
    float* Wf    = (float*)(ws + 186784512);          //   1,048,576
    float* bvec  = (float*)(ws + 187833088);          //       2,048

    hipMemsetAsync(icnt, 0, 40000, stream);

    cvt_transpose_kernel<<<(HID * K1 + 255) / 256, 256, 0, stream>>>(msg_w1, w1T, K1, HID);
    cvt_transpose_kernel<<<(HID * HID + 255) / 256, 256, 0, stream>>>(self_w, swT, HID, HID);
    wcombine_kernel<<<HID + 1, HID, 0, stream>>>(msg_w2, agg_w, msg_b2, Wf, bvec);
    cvt_transpose_kernel<<<(HID * HID + 255) / 256, 256, 0, stream>>>(Wf, WT, HID, HID);

    count_int_kernel<<<(N_EDGES + 255) / 256, 256, 0, stream>>>(tgts, icnt);
    scan_kernel<<<1, 256, 0, stream>>>(icnt, off, cursor);
    fill_kernel<<<(N_EDGES + 255) / 256, 256, 0, stream>>>(tgts, cursor, sorted);

    edge_mlp_kernel<1><<<N_EDGES / BM, 512, 0, stream>>>(
        node_state, edge_emb, srcs, tgts, w1T, msg_b1, nullptr, hs);

    gather_mean_kernel<<<(N_NODES + 3) / 4, 256, 0, stream>>>(hs, off, sorted, hmean);

    node_update_kernel<<<(N_NODES + BM - 1) / BM, 512, 0, stream>>>(
        node_state, hmean, icnt, swT, WT, self_b, agg_b, bvec, ln_gamma, ln_beta, out);
  } else {
    // ---- fallback: atomic scatter path (round-1 structure) ----
    float* hsum = (float*)ws;                         // 20,480,000
    int* icnt   = (int*)(ws + 20480000);              //     40,000
    short* w1T  = (short*)(ws + 20520192);            //    655,360
    short* swT  = (short*)(ws + 21175552);            //    524,288
    short* WT   = (short*)(ws + 21699840);            //    524,288
    float* Wf   = (float*)(ws + 22224128);            //  1,048,576
    float* bvec = (float*)(ws + 23272704);            //      2,048

    hipMemsetAsync(ws, 0, 20520000, stream);

    cvt_transpose_kernel<<<(HID * K1 + 255) / 256, 256, 0, stream>>>(msg_w1, w1T, K1, HID);
    cvt_transpose_kernel<<<(HID * HID + 255) / 256, 256, 0, stream>>>(self_w, swT, HID, HID);
    wcombine_kernel<<<HID + 1, HID, 0, stream>>>(msg_w2, agg_w, msg_b2, Wf, bvec);
    cvt_transpose_kernel<<<(HID * HID + 255) / 256, 256, 0, stream>>>(Wf, WT, HID, HID);
    count_int_kernel<<<(N_EDGES + 255) / 256, 256, 0, stream>>>(tgts, icnt);

    edge_mlp_kernel<0><<<N_EDGES / BM, 512, 0, stream>>>(
        node_state, edge_emb, srcs, tgts, w1T, msg_b1, hsum, nullptr);

    mean_div_kernel<<<(N_NODES * HID + 255) / 256, 256, 0, stream>>>(hsum, icnt);

    node_update_kernel<<<(N_NODES + BM - 1) / BM, 512, 0, stream>>>(
        node_state, hsum, icnt, swT, WT, self_b, agg_b, bvec, ln_gamma, ln_beta, out);
  }
}

// Round 3
// 321.658 us; speedup vs baseline: 1.3915x; 1.1652x over previous
//
#include <hip/hip_runtime.h>
#include <stdint.h>

#define N_NODES 10000
#define N_EDGES 160000
#define HID 512
#define EDIM 128
#define K1 640
#define BM 64
#define LN_EPS 1e-5f

typedef __attribute__((ext_vector_type(4))) float f32x4;
typedef __attribute__((ext_vector_type(8))) short bf16x8;

__device__ __forceinline__ short f2bf(float f) {
  unsigned u = __float_as_uint(f);
  u += 0x7fff + ((u >> 16) & 1);
  return (short)(u >> 16);
}
// tanh-form GELU: x * sigmoid(1.5957691*(x + 0.044715 x^3))
__device__ __forceinline__ float gelu_f(float x) {
  float t = x * x;
  float zn = x * fmaf(t, -0.07135472f, -1.59576912f);
  return x * __builtin_amdgcn_rcpf(1.0f + __expf(zn));
}

#define GLDS(g, l) __builtin_amdgcn_global_load_lds( \
    (const __attribute__((address_space(1))) void*)(g), \
    (__attribute__((address_space(3))) void*)(l), 16, 0, 0)

// ---------------------------------------------------------------------------
// Edge kernel: h = gelu([ns_bf[src] | ee] @ w1 + b1), edges in target-sorted
// order; epilogue does segmented column-sums and atomically adds into hsum.
// ---------------------------------------------------------------------------
__global__ __launch_bounds__(512, 4) void edge_mlp_kernel(
    const short* __restrict__ ns_bf, const float* __restrict__ edge_emb,
    const int* __restrict__ srcs, const int* __restrict__ tgts,
    const int* __restrict__ sorted,
    const short* __restrict__ w1T,  // [512 n][640 k] bf16
    const float* __restrict__ b1,
    float* __restrict__ hsum)
{
  __shared__ short As[2][BM * 32];     // 64 rows x 32 k, XOR-permuted 16B units
  __shared__ short Bs[2][HID * 32];    // 512 n x 32 k, XOR-permuted 16B units
  __shared__ int src_l[BM], tgt_l[BM], eid_l[BM];

  const int tid = threadIdx.x;
  const int lane = tid & 63;
  const int wv = tid >> 6;
  const int r16 = lane & 15, q4 = lane >> 4;
  const int e0 = blockIdx.x * BM;

  if (tid < BM) {
    int eid = sorted[e0 + tid];
    eid_l[tid] = eid;
    src_l[tid] = srcs[eid];
    tgt_l[tid] = tgts[eid];
  }

  float b1v[4];
#pragma unroll
  for (int ni = 0; ni < 4; ++ni) b1v[ni] = b1[wv * 64 + ni * 16 + r16];

  __syncthreads();

  // per-lane global source for A glds (ns region, k<512), inverse-XOR swizzled
  const int ar = (wv < 4) ? (wv * 16 + (lane >> 2)) : 0;
  const int auk = (((lane & 3) - (ar >> 1)) & 3);
  const short* nsrow = ns_bf + (size_t)src_l[ar] * HID + auk * 8;

  auto stageA = [&](int k0, int buf) {
    if (wv < 4) GLDS(nsrow + k0, &As[buf][wv * 512]);
  };
  auto stageB = [&](int k0, int buf) {
#pragma unroll
    for (int i = 0; i < 4; ++i) {
      int q = i * 512 + tid;                  // LDS 16B-unit position
      int n = q >> 2;
      int uk = ((q & 3) - (n >> 1)) & 3;      // inverse of read-side XOR
      const short* g = w1T + (size_t)n * K1 + k0 + uk * 8;
      short* l = &Bs[buf][(i * 512 + wv * 64) * 8];  // wave-uniform base
      GLDS(g, l);
    }
  };

  // ee region (k>=512): reg-staged f32 -> bf16
  f32x4 ea0, ea1;
  auto loadAee = [&](int k0) {
    if (tid < 256) {
      const float* p = edge_emb + (size_t)eid_l[tid >> 2] * EDIM + (k0 - HID) + (tid & 3) * 8;
      ea0 = *(const f32x4*)p; ea1 = *(const f32x4*)(p + 4);
    }
  };
  auto writeAee = [&](int buf) {
    if (tid < 256) {
      int r = tid >> 2, c = tid & 3;
      bf16x8 v;
      v[0] = f2bf(ea0[0]); v[1] = f2bf(ea0[1]); v[2] = f2bf(ea0[2]); v[3] = f2bf(ea0[3]);
      v[4] = f2bf(ea1[0]); v[5] = f2bf(ea1[1]); v[6] = f2bf(ea1[2]); v[7] = f2bf(ea1[3]);
      int pos = r * 4 + ((c + (r >> 1)) & 3);
      *(bf16x8*)(&As[buf][pos * 8]) = v;
    }
  };

  f32x4 acc[4][4] = {};

  auto mma = [&](int buf) {
    bf16x8 af[4];
#pragma unroll
    for (int mi = 0; mi < 4; ++mi) {
      int row = mi * 16 + r16;
      int pos = row * 4 + ((q4 + (row >> 1)) & 3);
      af[mi] = *(const bf16x8*)(&As[buf][pos * 8]);
    }
#pragma unroll
    for (int ni = 0; ni < 4; ++ni) {
      int n = wv * 64 + ni * 16 + r16;
      int pos = n * 4 + ((q4 + (n >> 1)) & 3);
      bf16x8 bfr = *(const bf16x8*)(&Bs[buf][pos * 8]);
#pragma unroll
      for (int mi = 0; mi < 4; ++mi)
        acc[mi][ni] = __builtin_amdgcn_mfma_f32_16x16x32_bf16(af[mi], bfr, acc[mi][ni], 0, 0, 0);
    }
  };

  stageB(0, 0);
  stageA(0, 0);
  __syncthreads();
#pragma unroll 1
  for (int s = 0; s < 20; ++s) {
    int cur = s & 1, nxt = cur ^ 1;
    int k0n = (s + 1) * 32;
    if (s < 19) {
      stageB(k0n, nxt);
      if (k0n < HID) stageA(k0n, nxt);
      else loadAee(k0n);
    }
    mma(cur);
    if (s < 19 && k0n >= HID) writeAee(nxt);
    __syncthreads();
  }

  // ---- epilogue: bias + gelu, segmented column-sum over sorted targets ----
#pragma unroll
  for (int mi = 0; mi < 4; ++mi)
#pragma unroll
    for (int ni = 0; ni < 4; ++ni)
#pragma unroll
      for (int j = 0; j < 4; ++j)
        acc[mi][ni][j] = gelu_f(acc[mi][ni][j] + b1v[ni]);

  // boundary mask (same in every wave): rows == lanes (BM == 64)
  int prev_t = (lane == 0) ? -1 : tgt_l[lane - 1];
  bool bnd = (lane == 0) || (tgt_l[lane] != prev_t);
  unsigned long long bmask = __ballot(bnd);

  int s = 0;
  while (s < BM) {
    int t = tgt_l[s];
    unsigned long long above = (s < 63) ? (bmask >> (s + 1)) : 0ull;
    int e = (above == 0ull) ? BM : (s + 1 + (int)__builtin_ctzll(above));

    float sum[4] = {0.f, 0.f, 0.f, 0.f};
#pragma unroll
    for (int mi = 0; mi < 4; ++mi)
#pragma unroll
      for (int j = 0; j < 4; ++j) {
        int row = mi * 16 + q4 * 4 + j;
        bool in = (row >= s) && (row < e);
#pragma unroll
        for (int ni = 0; ni < 4; ++ni)
          sum[ni] += in ? acc[mi][ni][j] : 0.0f;
      }
#pragma unroll
    for (int ni = 0; ni < 4; ++ni) {
      sum[ni] += __shfl_xor(sum[ni], 16, 64);
      sum[ni] += __shfl_xor(sum[ni], 32, 64);
    }
    if (q4 == 0) {
      float* dst = hsum + (size_t)t * HID + wv * 64 + r16;
#pragma unroll
      for (int ni = 0; ni < 4; ++ni) atomicAdd(dst + ni * 16, sum[ni]);
    }
    s = e;
  }
}

// ---------------------------------------------------------------------------
// Node kernel: updated = [ns | hsum*invc] @ [[self_w],[W]] + biases;
// out = LN(ns + gelu(updated)) * gamma + beta
// ---------------------------------------------------------------------------
__global__ __launch_bounds__(512, 2) void node_update_kernel(
    const float* __restrict__ node_state, const float* __restrict__ hsum,
    const int* __restrict__ icnt,
    const short* __restrict__ swT, const short* __restrict__ WT,  // [512 n][512 k]
    const float* __restrict__ self_b, const float* __restrict__ agg_b,
    const float* __restrict__ bvec,
    const float* __restrict__ gamma, const float* __restrict__ beta,
    float* __restrict__ out)
{
  __shared__ short As[2][BM * 32];
  __shared__ short Bs[2][HID * 32];
  __shared__ float cfl[BM], invc_l[BM];
  __shared__ float wsum[8][BM], wsq[8][BM];
  __shared__ float stats[BM][2];

  const int tid = threadIdx.x, lane = tid & 63, wv = tid >> 6;
  const int r16 = lane & 15, q4 = lane >> 4;
  const int n0 = blockIdx.x * BM;

  if (tid < BM) {
    int g = n0 + tid;
    int c = (g < N_NODES) ? icnt[g] : 0;
    cfl[tid] = (c > 0) ? 1.0f : 0.0f;
    invc_l[tid] = 1.0f / (float)max(c, 1);
  }

  float bb[4], bv[4], gam[4], bet[4];
#pragma unroll
  for (int ni = 0; ni < 4; ++ni) {
    int c = wv * 64 + ni * 16 + r16;
    bb[ni] = self_b[c] + agg_b[c];
    bv[ni] = bvec[c];
    gam[ni] = gamma[c]; bet[ni] = beta[c];
  }
  __syncthreads();

  const int arow = tid >> 2, auk = tid & 3;
  const int ga = min(n0 + arow, N_NODES - 1);
  f32x4 a0, a1;

  auto loadA = [&](int k0) {
    if (tid < 256) {
      int k = k0 + auk * 8;
      const float* p = (k < HID) ? node_state + (size_t)ga * HID + k
                                 : hsum + (size_t)ga * HID + (k - HID);
      a0 = *(const f32x4*)p; a1 = *(const f32x4*)(p + 4);
      if (k >= HID) { float s = invc_l[arow]; a0 *= s; a1 *= s; }
    }
  };
  auto writeA = [&](int buf) {
    if (tid < 256) {
      bf16x8 v;
      v[0] = f2bf(a0[0]); v[1] = f2bf(a0[1]); v[2] = f2bf(a0[2]); v[3] = f2bf(a0[3]);
      v[4] = f2bf(a1[0]); v[5] = f2bf(a1[1]); v[6] = f2bf(a1[2]); v[7] = f2bf(a1[3]);
      int pos = arow * 4 + ((auk + (arow >> 1)) & 3);
      *(bf16x8*)(&As[buf][pos * 8]) = v;
    }
  };
  auto stageB = [&](const short* wT, int k0, int buf) {
#pragma unroll
    for (int i = 0; i < 4; ++i) {
      int q = i * 512 + tid;
      int n = q >> 2;
      int uk = ((q & 3) - (n >> 1)) & 3;
      const short* g = wT + (size_t)n * HID + k0 + uk * 8;
      short* l = &Bs[buf][(i * 512 + wv * 64) * 8];
      GLDS(g, l);
    }
  };

  f32x4 acc[4][4] = {};

  auto mma = [&](int buf) {
    bf16x8 af[4];
#pragma unroll
    for (int mi = 0; mi < 4; ++mi) {
      int row = mi * 16 + r16;
      int pos = row * 4 + ((q4 + (row >> 1)) & 3);
      af[mi] = *(const bf16x8*)(&As[buf][pos * 8]);
    }
#pragma unroll
    for (int ni = 0; ni < 4; ++ni) {
      int n = wv * 64 + ni * 16 + r16;
      int pos = n * 4 + ((q4 + (n >> 1)) & 3);
      bf16x8 bfr = *(const bf16x8*)(&Bs[buf][pos * 8]);
#pragma unroll
      for (int mi = 0; mi < 4; ++mi)
        acc[mi][ni] = __builtin_amdgcn_mfma_f32_16x16x32_bf16(af[mi], bfr, acc[mi][ni], 0, 0, 0);
    }
  };

  stageB(swT, 0, 0);
  loadA(0); writeA(0);
  __syncthreads();
#pragma unroll 1
  for (int s = 0; s < 32; ++s) {
    int cur = s & 1, nxt = cur ^ 1;
    if (s < 31) {
      int k0 = (s + 1) * 32;
      if (k0 < HID) stageB(swT, k0, nxt); else stageB(WT, k0 - HID, nxt);
      loadA(k0);
    }
    mma(cur);
    if (s < 31) writeA(nxt);
    __syncthreads();
  }

  // epilogue: bias + flag*bvec, gelu, residual; row LN via shfl + LDS
  float ps[4][4], ps2[4][4];
#pragma unroll
  for (int mi = 0; mi < 4; ++mi)
#pragma unroll
    for (int j = 0; j < 4; ++j) {
      int row = mi * 16 + q4 * 4 + j;
      int g = min(n0 + row, N_NODES - 1);
      float fl = cfl[row];
      float s1 = 0.f, s2 = 0.f;
#pragma unroll
      for (int ni = 0; ni < 4; ++ni) {
        float u = acc[mi][ni][j] + bb[ni] + fl * bv[ni];
        float ns = node_state[(size_t)g * HID + wv * 64 + ni * 16 + r16];
        float x = ns + gelu_f(u);
        acc[mi][ni][j] = x;
        s1 += x; s2 += x * x;
      }
      ps[mi][j] = s1; ps2[mi][j] = s2;
    }
#pragma unroll
  for (int mi = 0; mi < 4; ++mi)
#pragma unroll
    for (int j = 0; j < 4; ++j) {
#pragma unroll
      for (int m = 1; m < 16; m <<= 1) {
        ps[mi][j] += __shfl_xor(ps[mi][j], m, 64);
        ps2[mi][j] += __shfl_xor(ps2[mi][j], m, 64);
      }
    }
  if (r16 == 0) {
#pragma unroll
    for (int mi = 0; mi < 4; ++mi)
#pragma unroll
      for (int j = 0; j < 4; ++j) {
        int row = mi * 16 + q4 * 4 + j;
        wsum[wv][row] = ps[mi][j]; wsq[wv][row] = ps2[mi][j];
      }
  }
  __syncthreads();
  if (tid < BM) {
    float s1 = 0.f, s2 = 0.f;
#pragma unroll
    for (int k = 0; k < 8; ++k) { s1 += wsum[k][tid]; s2 += wsq[k][tid]; }
    float mu = s1 * (1.0f / HID);
    float var = s2 * (1.0f / HID) - mu * mu;
    stats[tid][0] = mu; stats[tid][1] = rsqrtf(var + LN_EPS);
  }
  __syncthreads();
#pragma unroll
  for (int mi = 0; mi < 4; ++mi)
#pragma unroll
    for (int j = 0; j < 4; ++j) {
      int row = mi * 16 + q4 * 4 + j;
      int g = n0 + row;
      if (g < N_NODES) {
        float mu = stats[row][0], rs = stats[row][1];
#pragma unroll
        for (int ni = 0; ni < 4; ++ni)
          out[(size_t)g * HID + wv * 64 + ni * 16 + r16] =
              (acc[mi][ni][j] - mu) * rs * gam[ni] + bet[ni];
      }
    }
}

// ---------------------------------------------------------------------------
// CSR build
// ---------------------------------------------------------------------------
__global__ void count_int_kernel(const int* __restrict__ tgt, int* __restrict__ icnt)
{
  int i = blockIdx.x * 256 + threadIdx.x;
  if (i < N_EDGES) atomicAdd(&icnt[tgt[i]], 1);
}

__global__ __launch_bounds__(256) void scan_kernel(const int* __restrict__ icnt,
                                                   int* __restrict__ cursor)
{
  __shared__ int sums[256];
  const int t = threadIdx.x;
  const int CH = 40;  // 256*40 = 10240 >= N_NODES
  int loc[CH];
  int s = 0;
#pragma unroll
  for (int i = 0; i < CH; ++i) {
    int idx = t * CH + i;
    int v = (idx < N_NODES) ? icnt[idx] : 0;
    loc[i] = s; s += v;
  }
  sums[t] = s;
  __syncthreads();
  for (int d = 1; d < 256; d <<= 1) {
    int v = (t >= d) ? sums[t - d] : 0;
    __syncthreads();
    sums[t] += v;
    __syncthreads();
  }
  int base = (t == 0) ? 0 : sums[t - 1];
#pragma unroll
  for (int i = 0; i < CH; ++i) {
    int idx = t * CH + i;
    if (idx < N_NODES) cursor[idx] = base + loc[i];
  }
}

__global__ void fill_kernel(const int* __restrict__ tgt, int* __restrict__ cursor,
                            int* __restrict__ sorted)
{
  int i = blockIdx.x * 256 + threadIdx.x;
  if (i < N_EDGES) {
    int tg = tgt[i];
    int p = atomicAdd(&cursor[tg], 1);
    sorted[p] = i;
  }
}

// ---------------------------------------------------------------------------
// Weight prep + bf16 conversion
// ---------------------------------------------------------------------------
__global__ void wcombine_kernel(const float* __restrict__ w2,
                                const float* __restrict__ aggw,
                                const float* __restrict__ b2,
                                float* __restrict__ Wf, float* __restrict__ bvec)
{
  __shared__ float rowbuf[HID];
  int k = blockIdx.x;  // 0..511 rows of w2; 512 => b2
  const float* row = (k == HID) ? b2 : (w2 + (size_t)k * HID);
  int n = threadIdx.x;
  rowbuf[n] = row[n];
  __syncthreads();
  float s = 0.f;
  for (int j = 0; j < HID; ++j) s = fmaf(rowbuf[j], aggw[(size_t)j * HID + n], s);
  if (k == HID) bvec[n] = s; else Wf[(size_t)k * HID + n] = s;
}

__global__ void cvt_transpose_kernel(const float* __restrict__ src,
                                     short* __restrict__ dst, int K, int Nn)
{
  int id = blockIdx.x * 256 + threadIdx.x;   // over n*K + k
  if (id < K * Nn) {
    int n = id / K, k = id - n * K;
    dst[id] = f2bf(src[(size_t)k * Nn + n]);
  }
}

__global__ void cvt_bf16_kernel(const float* __restrict__ src,
                                short* __restrict__ dst, int n8)
{
  int id = blockIdx.x * 256 + threadIdx.x;
  if (id < n8) {
    f32x4 a0 = *(const f32x4*)(src + (size_t)id * 8);
    f32x4 a1 = *(const f32x4*)(src + (size_t)id * 8 + 4);
    bf16x8 v;
    v[0] = f2bf(a0[0]); v[1] = f2bf(a0[1]); v[2] = f2bf(a0[2]); v[3] = f2bf(a0[3]);
    v[4] = f2bf(a1[0]); v[5] = f2bf(a1[1]); v[6] = f2bf(a1[2]); v[7] = f2bf(a1[3]);
    *(bf16x8*)(dst + (size_t)id * 8) = v;
  }
}

// ---------------------------------------------------------------------------
extern "C" void kernel_launch(void* const* d_in, const int* in_sizes, int n_in,
                              void* d_out, int out_size, void* d_ws, size_t ws_size,
                              hipStream_t stream)
{
  const float* node_state = (const float*)d_in[0];
  const int*   eidx       = (const int*)d_in[1];
  const float* edge_emb   = (const float*)d_in[2];
  const float* msg_w1     = (const float*)d_in[3];
  const float* msg_b1     = (const float*)d_in[4];
  const float* msg_w2     = (const float*)d_in[5];
  const float* msg_b2     = (const float*)d_in[6];
  const float* self_w     = (const float*)d_in[7];
  const float* self_b     = (const float*)d_in[8];
  const float* agg_w      = (const float*)d_in[9];
  const float* agg_b      = (const float*)d_in[10];
  const float* ln_gamma   = (const float*)d_in[11];
  const float* ln_beta    = (const float*)d_in[12];

  const int* srcs = eidx;
  const int* tgts = eidx + N_EDGES;
  float* out = (float*)d_out;
  char* ws = (char*)d_ws;

  float* hsum  = (float*)ws;                        // 20,480,000
  short* ns_bf = (short*)(ws + 20480000);           // 10,240,000
  int* icnt    = (int*)(ws + 30720000);             //     40,000
  int* cursor  = (int*)(ws + 30760192);             //     40,000
  int* sorted  = (int*)(ws + 30800384);             //    640,000
  short* w1T   = (short*)(ws + 31440384);           //    655,360
  short* swT   = (short*)(ws + 32095744);           //    524,288
  short* WT    = (short*)(ws + 32620032);           //    524,288
  float* Wf    = (float*)(ws + 33144320);           //  1,048,576
  float* bvec  = (float*)(ws + 34192896);           //      2,048

  hipMemsetAsync(hsum, 0, 20480000, stream);
  hipMemsetAsync(icnt, 0, 40000, stream);

  cvt_bf16_kernel<<<(N_NODES * HID / 8 + 255) / 256, 256, 0, stream>>>(
      node_state, ns_bf, N_NODES * HID / 8);
  cvt_transpose_kernel<<<(HID * K1 + 255) / 256, 256, 0, stream>>>(msg_w1, w1T, K1, HID);
  cvt_transpose_kernel<<<(HID * HID + 255) / 256, 256, 0, stream>>>(self_w, swT, HID, HID);
  wcombine_kernel<<<HID + 1, HID, 0, stream>>>(msg_w2, agg_w, msg_b2, Wf, bvec);
  cvt_transpose_kernel<<<(HID * HID + 255) / 256, 256, 0, stream>>>(Wf, WT, HID, HID);

  count_int_kernel<<<(N_EDGES + 255) / 256, 256, 0, stream>>>(tgts, icnt);
  scan_kernel<<<1, 256, 0, stream>>>(icnt, cursor);
  fill_kernel<<<(N_EDGES + 255) / 256, 256, 0, stream>>>(tgts, cursor, sorted);

  edge_mlp_kernel<<<N_EDGES / BM, 512, 0, stream>>>(
      ns_bf, edge_emb, srcs, tgts, sorted, w1T, msg_b1, hsum);

  node_update_kernel<<<(N_NODES + BM - 1) / BM, 512, 0, stream>>>(
      node_state, hsum, icnt, swT, WT, self_b, agg_b, bvec, ln_gamma, ln_beta, out);
}